// Round 6
// baseline (31955.862 us; speedup 1.0000x reference)
//
#include <hip/hip_runtime.h>
#include <cstdint>
#include <cstddef>

#define T_SEQ 4096
#define HSZ   512
#define NGATE 2048   // 4*HSZ
#define DIN   1024
#define NBC   32     // blocks per chain
#define HBC   16     // h-elements per block
#define S_SLOT 16    // exchange ring slots (power of 2)
#define CH0   68     // skewed LDS chunk stride, 64-col chunks (L0)
#define CH1   132    // skewed LDS chunk stride, 128-col chunks (L1)
#define FB_THRESH 1024  // sticky fallback threshold (stale sc0 polls)

typedef unsigned long long u64;
typedef unsigned int u32;

// agent-scope (LLC) ops — correct across XCDs
__device__ __forceinline__ u64 exld(const u64* p) {
  return __hip_atomic_load(p, __ATOMIC_RELAXED, __HIP_MEMORY_SCOPE_AGENT);
}
__device__ __forceinline__ void exst(u64* p, u64 v) {
  __hip_atomic_store(p, v, __ATOMIC_RELAXED, __HIP_MEMORY_SCOPE_AGENT);
}
__device__ __forceinline__ int pgld(const u32* p) {
  return (int)__hip_atomic_load(p, __ATOMIC_RELAXED, __HIP_MEMORY_SCOPE_AGENT);
}
__device__ __forceinline__ void pgst(u32* p, u32 v) {
  __hip_atomic_store(p, v, __ATOMIC_RELAXED, __HIP_MEMORY_SCOPE_AGENT);
}

// XCD-local fast path (exL buffers ONLY): plain store -> local L2 (L1 is write-through);
// sc0 load bypasses L1, reads the XCD-local L2. exL lines are never agent-stored after
// init, so no L2/LLC ping-pong (the R2 bug).
__device__ __forceinline__ u64 l2ld(const u64* p) {
  u64 v;
  asm volatile("global_load_dwordx2 %0, %1, off sc0\n\ts_waitcnt vmcnt(0)"
               : "=v"(v) : "v"(p) : "memory");
  return v;
}
__device__ __forceinline__ void l2st(u64* p, u64 v) {
  asm volatile("global_store_dwordx2 %0, %1, off" :: "v"(p), "v"(v) : "memory");
}

// fast activations
__device__ __forceinline__ float frcp(float x) { return __builtin_amdgcn_rcpf(x); }
__device__ __forceinline__ float fsig(float x) { return frcp(1.f + __expf(-x)); }
__device__ __forceinline__ float ftnh(float x) { return 1.f - 2.f * frcp(1.f + __expf(2.f * x)); }

// ---------------- init: zero all exchange buffers (agent scope -> LLC, no dirty L2 copies)
// ex base covers exG0,exG1,exL0,exL1 contiguously: 4 * 2 * S_SLOT * HSZ u64 = 65536
__global__ void init_sync_kernel(u64* ex, u32* prog) {
  const int tid = blockIdx.x * blockDim.x + threadIdx.x;
  if (tid < 4 * 2 * S_SLOT * HSZ) exst(&ex[tid], 0ull);
  if (tid < 4 * NBC) pgst(&prog[tid], 0u);
}

// ---------------- fp32 GEMM with bias: P[t,r] = sum_k X[t,k]*W[r,k] + bi[r] + bh[r] ----------------
__global__ __launch_bounds__(256, 2)
void gemm_bias_kernel(const float* __restrict__ Xf, const float* __restrict__ Xb,
                      const float* __restrict__ Wf, const float* __restrict__ Wb,
                      const float* __restrict__ bif, const float* __restrict__ bhf,
                      const float* __restrict__ bib, const float* __restrict__ bhb,
                      float* __restrict__ Pf, float* __restrict__ Pb, int K)
{
  const int dir = blockIdx.z;
  const float* X  = dir ? Xb  : Xf;
  const float* W  = dir ? Wb  : Wf;
  const float* bi = dir ? bib : bif;
  const float* bh = dir ? bhb : bhf;
  float* P        = dir ? Pb  : Pf;

  const int m0 = blockIdx.x * 128;
  const int n0 = blockIdx.y * 128;
  const int tid = threadIdx.x;
  const int lr = tid >> 1;
  const int lk = (tid & 1) * 8;

  __shared__ float As[16*128];
  __shared__ float Bs[16*128];

  float acc[8][8];
  #pragma unroll
  for (int i = 0; i < 8; ++i)
    #pragma unroll
    for (int j = 0; j < 8; ++j) acc[i][j] = 0.f;

  for (int k0 = 0; k0 < K; k0 += 16) {
    const float4 a0 = *(const float4*)(X + (size_t)(m0+lr)*K + k0 + lk);
    const float4 a1 = *(const float4*)(X + (size_t)(m0+lr)*K + k0 + lk + 4);
    const float4 b0 = *(const float4*)(W + (size_t)(n0+lr)*K + k0 + lk);
    const float4 b1 = *(const float4*)(W + (size_t)(n0+lr)*K + k0 + lk + 4);
    __syncthreads();
    As[(lk+0)*128+lr]=a0.x; As[(lk+1)*128+lr]=a0.y; As[(lk+2)*128+lr]=a0.z; As[(lk+3)*128+lr]=a0.w;
    As[(lk+4)*128+lr]=a1.x; As[(lk+5)*128+lr]=a1.y; As[(lk+6)*128+lr]=a1.z; As[(lk+7)*128+lr]=a1.w;
    Bs[(lk+0)*128+lr]=b0.x; Bs[(lk+1)*128+lr]=b0.y; Bs[(lk+2)*128+lr]=b0.z; Bs[(lk+3)*128+lr]=b0.w;
    Bs[(lk+4)*128+lr]=b1.x; Bs[(lk+5)*128+lr]=b1.y; Bs[(lk+6)*128+lr]=b1.z; Bs[(lk+7)*128+lr]=b1.w;
    __syncthreads();
    #pragma unroll
    for (int kk = 0; kk < 16; ++kk) {
      const float4 A0 = *(const float4*)(As + kk*128 + (tid&15)*8);
      const float4 A1 = *(const float4*)(As + kk*128 + (tid&15)*8 + 4);
      const float4 B0 = *(const float4*)(Bs + kk*128 + (tid>>4)*8);
      const float4 B1 = *(const float4*)(Bs + kk*128 + (tid>>4)*8 + 4);
      const float av[8] = {A0.x,A0.y,A0.z,A0.w,A1.x,A1.y,A1.z,A1.w};
      const float bv[8] = {B0.x,B0.y,B0.z,B0.w,B1.x,B1.y,B1.z,B1.w};
      #pragma unroll
      for (int i = 0; i < 8; ++i)
        #pragma unroll
        for (int j = 0; j < 8; ++j) acc[i][j] += av[i]*bv[j];
    }
  }
  const int tm = m0 + (tid&15)*8;
  const int tn = n0 + (tid>>4)*8;
  #pragma unroll
  for (int i = 0; i < 8; ++i) {
    #pragma unroll
    for (int j = 0; j < 8; ++j) {
      const int n = tn + j;
      P[(size_t)(tm+i)*NGATE + n] = acc[i][j] + bi[n] + bh[n];
    }
  }
}

// ---------------- fused persistent recurrence: XCD-local fast exchange + LLC fallback ----------------
// 256 blocks x 512 thr. chain = bid&7 (0:L0f 1:L0b 2:L1f 3:L1b, 4-7 exit), b = bid>>3 (0..31).
// If dispatch round-robins XCDs by bid%8, each chain's 32 blocks share one XCD:
//   fast path: publish h via plain store to exL (local L2), peers poll with sc0 loads.
//   exG (agent/LLC) always written too: consumed by L1's x-reads and by fallback pollers.
// exL and exG are DISJOINT buffers -> no plain/agent line ping-pong (R2's failure mode).
// Sticky per-thread fallback to exG after FB_THRESH stale polls -> correctness never
// depends on the mapping. Ring/guard (16 slots, every-8-steps, >= t-4) as R4/R5.
__global__ __launch_bounds__(512, 1)
void fused_recur_kernel(const float* __restrict__ Whh0_f, const float* __restrict__ Whh0_b,
                        const float* __restrict__ Wih1_f, const float* __restrict__ Whh1_f,
                        const float* __restrict__ bih1_f, const float* __restrict__ bhh1_f,
                        const float* __restrict__ Wih1_b, const float* __restrict__ Whh1_b,
                        const float* __restrict__ bih1_b, const float* __restrict__ bhh1_b,
                        const float* __restrict__ P_f, const float* __restrict__ P_b,
                        u64* exG0, u64* exG1, u64* exL0, u64* exL1,
                        u32* prog0, u32* prog1,
                        float* __restrict__ out)
{
  const int chain = blockIdx.x & 7;
  const int b     = blockIdx.x >> 3;
  if (chain >= 4) return;
  const int lay = chain >> 1;
  const int dir = chain & 1;
  const int tid  = threadIdx.x;
  const int lane = tid & 63;
  const int wv   = tid >> 6;

  __shared__ float xh[2][8*CH1];   // double-buffered skewed chunks (sized for L1)

  // lane = cc*8 + el*4 + g : 4 gates of an element on adjacent lanes, 8 col-chunks
  const int g  = lane & 3;
  const int el = (lane >> 2) & 1;
  const int cc = lane >> 3;             // 0..7
  const int e  = wv*2 + el;             // 0..15 per block
  const int grow = g*HSZ + b*HBC + e;   // global gate-row
  const bool red0 = (cc == 0);
  const bool pub  = red0 && (g == 0);

  if (lay == 0) {
    // ---------------- layer 0 ----------------
    const float* Whh = dir ? Whh0_b : Whh0_f;
    const float* P   = dir ? P_b    : P_f;
    u64* exLS = exL0 + (size_t)dir*S_SLOT*HSZ;
    u64* exGS = exG0 + (size_t)dir*S_SLOT*HSZ;
    u32* prS  = prog0 + dir*NBC;
    u32* prL1 = prog1 + dir*NBC;

    float4 w[16];   // 64 cols per lane, stays in registers (64 VGPR, cap 256)
    {
      const float4* wp = (const float4*)(Whh + (size_t)grow*HSZ + cc*64);
      #pragma unroll
      for (int j = 0; j < 16; ++j) w[j] = wp[j];
    }

    float creg = 0.f;
    float pv = 0.f;
    if (red0) pv = P[(size_t)(dir ? (T_SEQ-1) : 0)*NGATE + grow];
    bool fastH = true;

    for (int t = 0; t < T_SEQ; ++t) {
      // guard loads issued early (every 8 steps; verified after barrier)
      int gv = 0x7fffffff;
      if ((t & 7) == 0) {
        if (tid >= 64 && tid < 64+NBC)       gv = pgld(&prS[tid-64]);
        else if (tid >= 96 && tid < 96+NBC)  gv = pgld(&prL1[tid-96]);
      }
      // poll h_t: fast local-L2 path, sticky agent fallback
      {
        const u64* spL = exLS + (size_t)(t & (S_SLOT-1))*HSZ + tid;
        const u64* spG = exGS + (size_t)(t & (S_SLOT-1))*HSZ + tid;
        u64 v = fastH ? l2ld(spL) : exld(spG);
        int it = 0;
        while ((u32)(v >> 32) != (u32)t) {
          if (fastH && ++it > FB_THRESH) fastH = false;
          v = fastH ? l2ld(spL) : exld(spG);
        }
        xh[t & 1][(tid>>6)*CH0 + (tid & 63)] = __uint_as_float((u32)v);
      }
      __syncthreads();
      if (tid == 0) pgst(&prS[b], (u32)(t+1));   // epoch-t reads complete
      // next-step P prefetch
      float pvn = 0.f;
      if (red0 && t+1 < T_SEQ) pvn = P[(size_t)(dir ? (T_SEQ-2-t) : (t+1))*NGATE + grow];
      // guard verify (rare spin; load issued ~a step earlier)
      if (gv < t-4) {
        const u32* gp = (tid < 96) ? &prS[tid-64] : &prL1[tid-96];
        while (pgld(gp) < t-4) {}
      }
      // matvec: 16 float4 from chunk cc (conflict-free: 8 chunks x stride-68 floats)
      const float4* h4 = (const float4*)(xh[t & 1] + cc*CH0);
      float a0=0.f, a1=0.f, a2=0.f, a3=0.f;
      #pragma unroll
      for (int j = 0; j < 16; j += 4) {
        const float4 h0=h4[j], h1=h4[j+1], h2=h4[j+2], h3=h4[j+3];
        a0 += w[j].x*h0.x   + w[j].y*h0.y   + w[j].z*h0.z   + w[j].w*h0.w;
        a1 += w[j+1].x*h1.x + w[j+1].y*h1.y + w[j+1].z*h1.z + w[j+1].w*h1.w;
        a2 += w[j+2].x*h2.x + w[j+2].y*h2.y + w[j+2].z*h2.z + w[j+2].w*h2.w;
        a3 += w[j+3].x*h3.x + w[j+3].y*h3.y + w[j+3].z*h3.z + w[j+3].w*h3.w;
      }
      float acc = (a0+a1)+(a2+a3);
      acc += __shfl_xor(acc, 8);    // reduce over cc (lane bits 3,4,5)
      acc += __shfl_xor(acc, 16);
      acc += __shfl_xor(acc, 32);
      const float val = acc + pv;
      pv = pvn;
      const float av = (g == 2) ? ftnh(val) : fsig(val);
      const float f1 = __shfl_xor(av, 1);
      const float f2 = __shfl_xor(av, 2);
      const float f3 = __shfl_xor(av, 3);
      if (pub) {
        creg = f1*creg + av*f2;          // sig(f)*c + sig(i)*tanh(g)
        const float hnew = f3*ftnh(creg);
        const int hidx = b*HBC + e;
        const size_t off = (size_t)((t+1) & (S_SLOT-1))*HSZ + hidx;
        const u64 pkt = ((u64)(u32)(t+1) << 32) | (u64)__float_as_uint(hnew);
        l2st(exLS + off, pkt);    // XCD-local copy (peers)
        exst(exGS + off, pkt);    // LLC copy (L1 x-readers + fallback)
        if (t == T_SEQ-1) {
          out[dir*HSZ + hidx]        = creg;   // cell_memories layer 0
          out[2048 + dir*HSZ + hidx] = hnew;   // hidden_states layer 0
        }
      }
    }
  } else {
    // ---------------- layer 1 ----------------
    const float* Wih = dir ? Wih1_b : Wih1_f;
    const float* Whh = dir ? Whh1_b : Whh1_f;
    const float* biv = dir ? bih1_b : bih1_f;
    const float* bhv = dir ? bhh1_b : bhh1_f;
    u64* exX  = exG0 + (size_t)dir*S_SLOT*HSZ;   // x source = layer-0 outputs (cross-XCD, LLC)
    u64* exLS = exL1 + (size_t)dir*S_SLOT*HSZ;
    u64* exGS = exG1 + (size_t)dir*S_SLOT*HSZ;
    u32* prS  = prog1 + dir*NBC;

    float4 w[32];   // 128 cols per lane: cc<4 -> Wih/x, cc>=4 -> Whh/h (128 VGPR, cap 256)
    {
      const float* wsrc = (cc < 4) ? (Wih + (size_t)grow*HSZ + cc*128)
                                   : (Whh + (size_t)grow*HSZ + (cc-4)*128);
      const float4* wp = (const float4*)wsrc;
      #pragma unroll
      for (int j = 0; j < 32; ++j) w[j] = wp[j];
    }
    float brow = 0.f;
    if (red0) brow = biv[grow] + bhv[grow];

    float creg = 0.f;
    bool fastH = true;
    u64 xpf = exld(exX + (size_t)(1 & (S_SLOT-1))*HSZ + tid);   // prefetch x epoch 1

    for (int t = 0; t < T_SEQ; ++t) {
      int gv = 0x7fffffff;
      if ((t & 7) == 0 && tid >= 64 && tid < 64+NBC) gv = pgld(&prS[tid-64]);
      // poll x_t (epoch t+1 via agent prefetch) and own h_t (fast local path)
      {
        const u64* px  = exX  + (size_t)((t+1) & (S_SLOT-1))*HSZ + tid;
        const u64* spL = exLS + (size_t)(t & (S_SLOT-1))*HSZ + tid;
        const u64* spG = exGS + (size_t)(t & (S_SLOT-1))*HSZ + tid;
        u64 vx = xpf; bool okx = ((u32)(vx >> 32) == (u32)(t+1));
        u64 vh = fastH ? l2ld(spL) : exld(spG);
        bool okh = ((u32)(vh >> 32) == (u32)t);
        int it = 0;
        while (!(okx && okh)) {
          if (!okx) { u64 v2 = exld(px); if ((u32)(v2>>32) == (u32)(t+1)) { vx = v2; okx = true; } }
          if (!okh) {
            if (fastH && ++it > FB_THRESH) fastH = false;
            u64 v2 = fastH ? l2ld(spL) : exld(spG);
            if ((u32)(v2>>32) == (u32)t) { vh = v2; okh = true; }
          }
        }
        xh[t & 1][(tid>>7)*CH1 + (tid & 127)]       = __uint_as_float((u32)vx);   // chunks 0..3 (x)
        xh[t & 1][(4 + (tid>>7))*CH1 + (tid & 127)] = __uint_as_float((u32)vh);   // chunks 4..7 (h)
      }
      __syncthreads();
      if (tid == 0) pgst(&prS[b], (u32)(t+1));
      xpf = exld(exX + (size_t)((t+2) & (S_SLOT-1))*HSZ + tid);   // prefetch next x
      if (gv < t-4) { while (pgld(&prS[tid-64]) < t-4) {} }
      // matvec: 32 float4 from chunk cc
      const float4* h4 = (const float4*)(xh[t & 1] + cc*CH1);
      float a0=0.f, a1=0.f, a2=0.f, a3=0.f;
      #pragma unroll
      for (int j = 0; j < 32; j += 4) {
        const float4 h0=h4[j], h1=h4[j+1], h2=h4[j+2], h3=h4[j+3];
        a0 += w[j].x*h0.x   + w[j].y*h0.y   + w[j].z*h0.z   + w[j].w*h0.w;
        a1 += w[j+1].x*h1.x + w[j+1].y*h1.y + w[j+1].z*h1.z + w[j+1].w*h1.w;
        a2 += w[j+2].x*h2.x + w[j+2].y*h2.y + w[j+2].z*h2.z + w[j+2].w*h2.w;
        a3 += w[j+3].x*h3.x + w[j+3].y*h3.y + w[j+3].z*h3.z + w[j+3].w*h3.w;
      }
      float acc = (a0+a1)+(a2+a3);
      acc += __shfl_xor(acc, 8);    // reduce over cc (lane bits 3,4,5)
      acc += __shfl_xor(acc, 16);
      acc += __shfl_xor(acc, 32);
      const float val = acc + brow;
      const float av = (g == 2) ? ftnh(val) : fsig(val);
      const float f1 = __shfl_xor(av, 1);
      const float f2 = __shfl_xor(av, 2);
      const float f3 = __shfl_xor(av, 3);
      if (pub) {
        creg = f1*creg + av*f2;
        const float hnew = f3*ftnh(creg);
        const int hidx = b*HBC + e;
        const size_t off = (size_t)((t+1) & (S_SLOT-1))*HSZ + hidx;
        const u64 pkt = ((u64)(u32)(t+1) << 32) | (u64)__float_as_uint(hnew);
        l2st(exLS + off, pkt);
        exst(exGS + off, pkt);
        const int trow = dir ? (T_SEQ-1-t) : t;
        out[4096 + (size_t)trow*1024 + dir*HSZ + hidx] = hnew;   // top-layer outputs
        if (t == T_SEQ-1) {
          out[1024 + dir*HSZ + hidx]        = creg;   // cell_memories layer 1
          out[2048 + 1024 + dir*HSZ + hidx] = hnew;   // hidden_states layer 1
        }
      }
    }
  }
}

// ---------------- launch ----------------
extern "C" void kernel_launch(void* const* d_in, const int* in_sizes, int n_in,
                              void* d_out, int out_size, void* d_ws, size_t ws_size,
                              hipStream_t stream)
{
  const float* emb   = (const float*)d_in[0];
  const float* fWih0 = (const float*)d_in[1];
  const float* fWhh0 = (const float*)d_in[2];
  const float* fbih0 = (const float*)d_in[3];
  const float* fbhh0 = (const float*)d_in[4];
  const float* fWih1 = (const float*)d_in[5];
  const float* fWhh1 = (const float*)d_in[6];
  const float* fbih1 = (const float*)d_in[7];
  const float* fbhh1 = (const float*)d_in[8];
  const float* bWih0 = (const float*)d_in[9];
  const float* bWhh0 = (const float*)d_in[10];
  const float* bbih0 = (const float*)d_in[11];
  const float* bbhh0 = (const float*)d_in[12];
  const float* bWih1 = (const float*)d_in[13];
  const float* bWhh1 = (const float*)d_in[14];
  const float* bbih1 = (const float*)d_in[15];
  const float* bbhh1 = (const float*)d_in[16];
  float* out = (float*)d_out;

  // workspace: P[2][4096][2048] fp32 (67 MB), exG0/exG1/exL0/exL1 [2][S_SLOT][512] u64, flags
  float* P_f = (float*)d_ws;
  float* P_b = P_f + (size_t)T_SEQ*NGATE;
  u64*   exG0 = (u64*)(P_b + (size_t)T_SEQ*NGATE);
  u64*   exG1 = exG0 + 2*S_SLOT*HSZ;
  u64*   exL0 = exG1 + 2*S_SLOT*HSZ;
  u64*   exL1 = exL0 + 2*S_SLOT*HSZ;
  u32*   prog0 = (u32*)(exL1 + 2*S_SLOT*HSZ);
  u32*   prog1 = prog0 + 2*NBC;

  init_sync_kernel<<<64, 1024, 0, stream>>>(exG0, prog0);

  // layer-0 input projections for both directions (bwd reads P reversed in time)
  gemm_bias_kernel<<<dim3(32,16,2), 256, 0, stream>>>(
      emb, emb, fWih0, bWih0, fbih0, fbhh0, bbih0, bbhh0, P_f, P_b, DIN);

  // fused pipelined recurrence: chains pinned per-XCD by bid%8 (perf assumption only;
  // sticky agent fallback preserves correctness under any mapping)
  fused_recur_kernel<<<256, 512, 0, stream>>>(
      fWhh0, bWhh0,
      fWih1, fWhh1, fbih1, fbhh1,
      bWih1, bWhh1, bbih1, bbhh1,
      P_f, P_b, exG0, exG1, exL0, exL1, prog0, prog1, out);
}

// Round 9
// 12227.129 us; speedup vs baseline: 2.6135x; 2.6135x over previous
//
#include <hip/hip_runtime.h>
#include <cstdint>
#include <cstddef>

#define T_SEQ 4096
#define HSZ   512
#define NGATE 2048   // 4*HSZ
#define DIN   1024
#define NB0   16     // layer-0 blocks per direction
#define HB0   32     // h-elements per layer-0 block
#define NB1   32     // layer-1 blocks per direction
#define HB1   16     // h-elements per layer-1 block
#define S_SLOT 16    // exchange ring slots (power of 2)
#define CH    132    // skewed LDS chunk stride (128 + 4)

typedef unsigned long long u64;
typedef unsigned int u32;

__device__ __forceinline__ u64 exld(const u64* p) {
  return __hip_atomic_load(p, __ATOMIC_RELAXED, __HIP_MEMORY_SCOPE_AGENT);
}
__device__ __forceinline__ void exst(u64* p, u64 v) {
  __hip_atomic_store(p, v, __ATOMIC_RELAXED, __HIP_MEMORY_SCOPE_AGENT);
}
__device__ __forceinline__ int pgld(const u32* p) {
  return (int)__hip_atomic_load(p, __ATOMIC_RELAXED, __HIP_MEMORY_SCOPE_AGENT);
}
__device__ __forceinline__ void pgst(u32* p, u32 v) {
  __hip_atomic_store(p, v, __ATOMIC_RELAXED, __HIP_MEMORY_SCOPE_AGENT);
}

// wide coherent poll loads: 16B dwordx4 with sc0 sc1 (L1+L2 bypass -> LLC, agent-visible).
// Paired variant keeps both loads in flight before the waitcnt.
__device__ __forceinline__ ulonglong2 exld16(const u64* p) {
  ulonglong2 v;
  asm volatile("global_load_dwordx4 %0, %1, off sc0 sc1\n"
               "s_waitcnt vmcnt(0)"
               : "=&v"(v) : "v"(p) : "memory");
  return v;
}
__device__ __forceinline__ void exld16x2(const u64* p, ulonglong2& A, ulonglong2& B) {
  asm volatile("global_load_dwordx4 %0, %2, off sc0 sc1\n"
               "global_load_dwordx4 %1, %2, off offset:16 sc0 sc1\n"
               "s_waitcnt vmcnt(0)"
               : "=&v"(A), "=&v"(B) : "v"(p) : "memory");
}

// poll 4 consecutive u64 slots until all tags match; fast wide path with sticky
// fallback (after 2048 stale iters) to the known-good scalar agent-atomic path.
__device__ __forceinline__ void poll4(const u64* base, u32 tag, bool& fast, float4& out) {
  if (fast) {
    ulonglong2 A, B; bool okA = false, okB = false; int it = 0;
    while (!(okA && okB)) {
      ulonglong2 nA, nB;
      if (!okA && !okB) exld16x2(base, nA, nB);
      else if (!okA)    nA = exld16(base);
      else              nB = exld16(base + 2);
      if (!okA && (u32)(nA.x >> 32) == tag && (u32)(nA.y >> 32) == tag) { A = nA; okA = true; }
      if (!okB && (u32)(nB.x >> 32) == tag && (u32)(nB.y >> 32) == tag) { B = nB; okB = true; }
      if (++it > 2048) { fast = false; break; }
    }
    if (okA && okB) {
      out = make_float4(__uint_as_float((u32)A.x), __uint_as_float((u32)A.y),
                        __uint_as_float((u32)B.x), __uint_as_float((u32)B.y));
      return;
    }
  }
  u64 v0=0, v1=0, v2=0, v3=0; bool o0=false, o1=false, o2=false, o3=false;
  while (!(o0 && o1 && o2 && o3)) {
    if (!o0) { u64 v = exld(base+0); if ((u32)(v>>32) == tag) { v0 = v; o0 = true; } }
    if (!o1) { u64 v = exld(base+1); if ((u32)(v>>32) == tag) { v1 = v; o1 = true; } }
    if (!o2) { u64 v = exld(base+2); if ((u32)(v>>32) == tag) { v2 = v; o2 = true; } }
    if (!o3) { u64 v = exld(base+3); if ((u32)(v>>32) == tag) { v3 = v; o3 = true; } }
  }
  out = make_float4(__uint_as_float((u32)v0), __uint_as_float((u32)v1),
                    __uint_as_float((u32)v2), __uint_as_float((u32)v3));
}

// fast activations: v_rcp + v_exp (no div sequences, no libm tanh)
__device__ __forceinline__ float frcp(float x) { return __builtin_amdgcn_rcpf(x); }
__device__ __forceinline__ float fsig(float x) { return frcp(1.f + __expf(-x)); }
__device__ __forceinline__ float ftnh(float x) { return 1.f - 2.f * frcp(1.f + __expf(2.f * x)); }

// ---------------- init: zero exchange slots (epoch0 == h_0 == 0) + progress flags ----------------
__global__ void init_sync_kernel(u64* ex, u32* prog) {
  const int tid = blockIdx.x * blockDim.x + threadIdx.x;
  if (tid < 2 * 2 * S_SLOT * HSZ) exst(&ex[tid], 0ull);
  if (tid < 2 * (NB0 + NB1)) pgst(&prog[tid], 0u);
}

// ---------------- fp32 GEMM with bias: P[t,r] = sum_k X[t,k]*W[r,k] + bi[r] + bh[r] ----------------
__global__ __launch_bounds__(256, 2)
void gemm_bias_kernel(const float* __restrict__ Xf, const float* __restrict__ Xb,
                      const float* __restrict__ Wf, const float* __restrict__ Wb,
                      const float* __restrict__ bif, const float* __restrict__ bhf,
                      const float* __restrict__ bib, const float* __restrict__ bhb,
                      float* __restrict__ Pf, float* __restrict__ Pb, int K)
{
  const int dir = blockIdx.z;
  const float* X  = dir ? Xb  : Xf;
  const float* W  = dir ? Wb  : Wf;
  const float* bi = dir ? bib : bif;
  const float* bh = dir ? bhb : bhf;
  float* P        = dir ? Pb  : Pf;

  const int m0 = blockIdx.x * 128;
  const int n0 = blockIdx.y * 128;
  const int tid = threadIdx.x;
  const int lr = tid >> 1;
  const int lk = (tid & 1) * 8;

  __shared__ float As[16*128];
  __shared__ float Bs[16*128];

  float acc[8][8];
  #pragma unroll
  for (int i = 0; i < 8; ++i)
    #pragma unroll
    for (int j = 0; j < 8; ++j) acc[i][j] = 0.f;

  for (int k0 = 0; k0 < K; k0 += 16) {
    const float4 a0 = *(const float4*)(X + (size_t)(m0+lr)*K + k0 + lk);
    const float4 a1 = *(const float4*)(X + (size_t)(m0+lr)*K + k0 + lk + 4);
    const float4 b0 = *(const float4*)(W + (size_t)(n0+lr)*K + k0 + lk);
    const float4 b1 = *(const float4*)(W + (size_t)(n0+lr)*K + k0 + lk + 4);
    __syncthreads();
    As[(lk+0)*128+lr]=a0.x; As[(lk+1)*128+lr]=a0.y; As[(lk+2)*128+lr]=a0.z; As[(lk+3)*128+lr]=a0.w;
    As[(lk+4)*128+lr]=a1.x; As[(lk+5)*128+lr]=a1.y; As[(lk+6)*128+lr]=a1.z; As[(lk+7)*128+lr]=a1.w;
    Bs[(lk+0)*128+lr]=b0.x; Bs[(lk+1)*128+lr]=b0.y; Bs[(lk+2)*128+lr]=b0.z; Bs[(lk+3)*128+lr]=b0.w;
    Bs[(lk+4)*128+lr]=b1.x; Bs[(lk+5)*128+lr]=b1.y; Bs[(lk+6)*128+lr]=b1.z; Bs[(lk+7)*128+lr]=b1.w;
    __syncthreads();
    #pragma unroll
    for (int kk = 0; kk < 16; ++kk) {
      const float4 A0 = *(const float4*)(As + kk*128 + (tid&15)*8);
      const float4 A1 = *(const float4*)(As + kk*128 + (tid&15)*8 + 4);
      const float4 B0 = *(const float4*)(Bs + kk*128 + (tid>>4)*8);
      const float4 B1 = *(const float4*)(Bs + kk*128 + (tid>>4)*8 + 4);
      const float av[8] = {A0.x,A0.y,A0.z,A0.w,A1.x,A1.y,A1.z,A1.w};
      const float bv[8] = {B0.x,B0.y,B0.z,B0.w,B1.x,B1.y,B1.z,B1.w};
      #pragma unroll
      for (int i = 0; i < 8; ++i)
        #pragma unroll
        for (int j = 0; j < 8; ++j) acc[i][j] += av[i]*bv[j];
    }
  }
  const int tm = m0 + (tid&15)*8;
  const int tn = n0 + (tid>>4)*8;
  #pragma unroll
  for (int i = 0; i < 8; ++i) {
    #pragma unroll
    for (int j = 0; j < 8; ++j) {
      const int n = tn + j;
      P[(size_t)(tm+i)*NGATE + n] = acc[i][j] + bi[n] + bh[n];
    }
  }
}

// ---------------- fused persistent recurrence: both layers, both directions, pipelined ----------------
// blocks [0,16): L0 fwd   [16,32): L0 bwd   [32,64): L1 fwd   [64,96): L1 bwd
// Exchange: u64 = (epoch<<32)|float_bits into slot epoch&(S_SLOT-1), agent scope (LLC).
// R4: 16-slot ring + lazy guard (every 8 steps, >= t-4).  R5: in-wave gates, 1 barrier/step.
// R7: (a) weights pinned in VGPRs (launch_bounds(512,1) + opaque-asm liveness: VGPR was 92 <
// the 128-reg weight array -> compiler reloaded weights from cache every step);
// (b) consolidated polling: waves 0-1 poll h (and waves 2-3 poll x in L1) via 16B sc0sc1
// loads, 4 slots/lane -> ~4x fewer LLC poll requests; idle waves go straight to barrier.
// Sticky scalar-atomic fallback preserves correctness if sc-flag semantics are off.
__global__ __launch_bounds__(512, 1)
void fused_recur_kernel(const float* __restrict__ Whh0_f, const float* __restrict__ Whh0_b,
                        const float* __restrict__ Wih1_f, const float* __restrict__ Whh1_f,
                        const float* __restrict__ bih1_f, const float* __restrict__ bhh1_f,
                        const float* __restrict__ Wih1_b, const float* __restrict__ Whh1_b,
                        const float* __restrict__ bih1_b, const float* __restrict__ bhh1_b,
                        const float* __restrict__ P_f, const float* __restrict__ P_b,
                        u64* ex0, u64* ex1, u32* prog0, u32* prog1,
                        float* __restrict__ out)
{
  const int bx  = blockIdx.x;
  const int tid = threadIdx.x;
  const int lane = tid & 63;
  const int wv   = tid >> 6;

  __shared__ float xh[2][8*CH];   // double-buffered skewed chunks

  if (bx < 2*NB0) {
    // ---------------- layer 0 ----------------
    const int dir = (bx >= NB0) ? 1 : 0;
    const int b   = bx - dir*NB0;
    const float* Whh = dir ? Whh0_b : Whh0_f;
    const float* P   = dir ? P_b    : P_f;
    u64* exS   = ex0 + (size_t)dir*S_SLOT*HSZ;   // self exchange (also read by layer 1)
    u32* prS   = prog0 + dir*NB0;
    u32* prL1  = prog1 + dir*NB1;

    // lane = cc*16 + e_low*4 + g : 4 gates of an element on adjacent lanes
    const int g  = lane & 3;
    const int el = (lane >> 2) & 3;
    const int cc = lane >> 4;            // col chunk 0..3 (128 cols each)
    const int e  = wv*4 + el;            // 0..31 per block
    const int grow = g*HSZ + b*HB0 + e;  // global gate-row
    const bool red0 = (cc == 0);
    const bool pub  = red0 && (g == 0);

    float4 w[32];
    {
      const float4* wp = (const float4*)(Whh + (size_t)grow*HSZ + cc*128);
      #pragma unroll
      for (int j = 0; j < 32; ++j) w[j] = wp[j];
    }
    // pin weights in VGPRs: opaque asm makes rematerialization-from-memory impossible
    #pragma unroll
    for (int j = 0; j < 32; ++j)
      asm volatile("" : "+v"(w[j].x), "+v"(w[j].y), "+v"(w[j].z), "+v"(w[j].w));

    float creg = 0.f;
    float pv = 0.f;
    if (red0) pv = P[(size_t)(dir ? (T_SEQ-1) : 0)*NGATE + grow];
    bool fastH = true;

    for (int t = 0; t < T_SEQ; ++t) {
      // slot-overwrite guard on idle lanes, every 8 steps
      if ((t & 7) == 0) {
        if (tid >= 256 && tid < 256+NB0)      { while (pgld(&prS[tid-256])  < t-4) {} }
        else if (tid >= 288 && tid < 288+NB1) { while (pgld(&prL1[tid-288]) < t-4) {} }
      }
      // consolidated h-poll: waves 0-1, 4 slots/lane, wide loads
      if (tid < 128) {
        float4 hv4;
        poll4(exS + (size_t)(t & (S_SLOT-1))*HSZ + 4*tid, (u32)t, fastH, hv4);
        *(float4*)&xh[t & 1][(tid>>5)*CH + 4*(tid&31)] = hv4;
      }
      __syncthreads();
      if (tid == 256) pgst(&prS[b], (u32)(t+1));   // epoch-t reads complete
      // next-step P prefetch (one step of miss-hiding)
      float pvn = 0.f;
      if (red0 && t+1 < T_SEQ) pvn = P[(size_t)(dir ? (T_SEQ-2-t) : (t+1))*NGATE + grow];
      // matvec: lane covers 128 cols (chunk cc) of its row
      const float4* h4 = (const float4*)(xh[t & 1] + cc*CH);
      float a0=0.f, a1=0.f, a2=0.f, a3=0.f;
      #pragma unroll
      for (int j = 0; j < 32; j += 4) {
        const float4 h0 = h4[j], h1 = h4[j+1], h2 = h4[j+2], h3 = h4[j+3];
        a0 += w[j].x*h0.x   + w[j].y*h0.y   + w[j].z*h0.z   + w[j].w*h0.w;
        a1 += w[j+1].x*h1.x + w[j+1].y*h1.y + w[j+1].z*h1.z + w[j+1].w*h1.w;
        a2 += w[j+2].x*h2.x + w[j+2].y*h2.y + w[j+2].z*h2.z + w[j+2].w*h2.w;
        a3 += w[j+3].x*h3.x + w[j+3].y*h3.y + w[j+3].z*h3.z + w[j+3].w*h3.w;
      }
      float acc = (a0+a1)+(a2+a3);
      acc += __shfl_xor(acc, 16);          // reduce over cc (lane bits 4,5)
      acc += __shfl_xor(acc, 32);
      const float val = acc + pv;          // full row value on cc==0 lanes
      pv = pvn;
      // parallel activation on the 4 gate lanes, then gather
      const float av = (g == 2) ? ftnh(val) : fsig(val);
      const float f1 = __shfl_xor(av, 1);
      const float f2 = __shfl_xor(av, 2);
      const float f3 = __shfl_xor(av, 3);
      if (pub) {
        // lane g=0: av=sig(i); f1=sig(f); f2=tanh(g); f3=sig(o)
        creg = f1*creg + av*f2;
        const float hnew = f3*ftnh(creg);
        const int hidx = b*HB0 + e;
        const u64 pkt = ((u64)(u32)(t+1) << 32) | (u64)__float_as_uint(hnew);
        exst(exS + (size_t)((t+1) & (S_SLOT-1))*HSZ + hidx, pkt);
        if (t == T_SEQ-1) {
          out[dir*HSZ + hidx]        = creg;   // cell_memories layer 0
          out[2048 + dir*HSZ + hidx] = hnew;   // hidden_states layer 0
        }
      }
    }
  } else {
    // ---------------- layer 1 ----------------
    const int r   = bx - 2*NB0;
    const int dir = (r >= NB1) ? 1 : 0;
    const int b   = r - dir*NB1;
    const float* Wih = dir ? Wih1_b : Wih1_f;
    const float* Whh = dir ? Whh1_b : Whh1_f;
    const float* bi  = dir ? bih1_b : bih1_f;
    const float* bh  = dir ? bhh1_b : bhh1_f;
    u64* exX = ex0 + (size_t)dir*S_SLOT*HSZ;     // x source = layer-0 outputs
    u64* exS = ex1 + (size_t)dir*S_SLOT*HSZ;     // self h exchange
    u32* prS = prog1 + dir*NB1;

    // lane = sub*8 + e_low*4 + g
    const int g   = lane & 3;
    const int el  = (lane >> 2) & 1;
    const int sub = lane >> 3;           // 0..7 col chunk (0-3: Wih/x, 4-7: Whh/h)
    const int e   = wv*2 + el;           // 0..15 per block
    const int grow = g*HSZ + b*HB1 + e;
    const bool red0 = (sub == 0);
    const bool pub  = red0 && (g == 0);

    float4 w[32];
    {
      const float* wsrc = (sub < 4) ? (Wih + (size_t)grow*HSZ + sub*128)
                                    : (Whh + (size_t)grow*HSZ + (sub-4)*128);
      const float4* wp = (const float4*)wsrc;
      #pragma unroll
      for (int j = 0; j < 32; ++j) w[j] = wp[j];
    }
    #pragma unroll
    for (int j = 0; j < 32; ++j)
      asm volatile("" : "+v"(w[j].x), "+v"(w[j].y), "+v"(w[j].z), "+v"(w[j].w));

    float brow = 0.f;
    if (red0) brow = bi[grow] + bh[grow];

    float creg = 0.f;
    bool fastX = true, fastH = true;

    for (int t = 0; t < T_SEQ; ++t) {
      // slot-overwrite guard on idle lanes, every 8 steps
      if ((t & 7) == 0 && tid >= 256 && tid < 256+NB1) { while (pgld(&prS[tid-256]) < t-4) {} }
      // consolidated polls: waves 0-1 -> x (epoch t+1), waves 2-3 -> own h (epoch t)
      if (tid < 128) {
        float4 xv4;
        poll4(exX + (size_t)((t+1) & (S_SLOT-1))*HSZ + 4*tid, (u32)(t+1), fastX, xv4);
        *(float4*)&xh[t & 1][(tid>>5)*CH + 4*(tid&31)] = xv4;           // chunks 0..3 (x)
      } else if (tid < 256) {
        const int p2 = tid - 128;
        float4 hv4;
        poll4(exS + (size_t)(t & (S_SLOT-1))*HSZ + 4*p2, (u32)t, fastH, hv4);
        *(float4*)&xh[t & 1][(4 + (p2>>5))*CH + 4*(p2&31)] = hv4;       // chunks 4..7 (h)
      }
      __syncthreads();
      if (tid == 256) pgst(&prS[b], (u32)(t+1));
      const float4* v4 = (const float4*)(xh[t & 1] + sub*CH);
      float a0=0.f, a1=0.f, a2=0.f, a3=0.f;
      #pragma unroll
      for (int j = 0; j < 32; j += 4) {
        const float4 h0 = v4[j], h1 = v4[j+1], h2 = v4[j+2], h3 = v4[j+3];
        a0 += w[j].x*h0.x   + w[j].y*h0.y   + w[j].z*h0.z   + w[j].w*h0.w;
        a1 += w[j+1].x*h1.x + w[j+1].y*h1.y + w[j+1].z*h1.z + w[j+1].w*h1.w;
        a2 += w[j+2].x*h2.x + w[j+2].y*h2.y + w[j+2].z*h2.z + w[j+2].w*h2.w;
        a3 += w[j+3].x*h3.x + w[j+3].y*h3.y + w[j+3].z*h3.z + w[j+3].w*h3.w;
      }
      float acc = (a0+a1)+(a2+a3);
      acc += __shfl_xor(acc, 8);           // reduce over sub (lane bits 3,4,5)
      acc += __shfl_xor(acc, 16);
      acc += __shfl_xor(acc, 32);
      const float val = acc + brow;
      const float av = (g == 2) ? ftnh(val) : fsig(val);
      const float f1 = __shfl_xor(av, 1);
      const float f2 = __shfl_xor(av, 2);
      const float f3 = __shfl_xor(av, 3);
      if (pub) {
        creg = f1*creg + av*f2;
        const float hnew = f3*ftnh(creg);
        const int hidx = b*HB1 + e;
        const u64 pkt = ((u64)(u32)(t+1) << 32) | (u64)__float_as_uint(hnew);
        exst(exS + (size_t)((t+1) & (S_SLOT-1))*HSZ + hidx, pkt);
        const int trow = dir ? (T_SEQ-1-t) : t;
        out[4096 + (size_t)trow*1024 + dir*HSZ + hidx] = hnew;   // top-layer outputs
        if (t == T_SEQ-1) {
          out[1024 + dir*HSZ + hidx]        = creg;   // cell_memories layer 1
          out[2048 + 1024 + dir*HSZ + hidx] = hnew;   // hidden_states layer 1
        }
      }
    }
  }
}

// ---------------- launch ----------------
extern "C" void kernel_launch(void* const* d_in, const int* in_sizes, int n_in,
                              void* d_out, int out_size, void* d_ws, size_t ws_size,
                              hipStream_t stream)
{
  const float* emb   = (const float*)d_in[0];
  const float* fWih0 = (const float*)d_in[1];
  const float* fWhh0 = (const float*)d_in[2];
  const float* fbih0 = (const float*)d_in[3];
  const float* fbhh0 = (const float*)d_in[4];
  const float* fWih1 = (const float*)d_in[5];
  const float* fWhh1 = (const float*)d_in[6];
  const float* fbih1 = (const float*)d_in[7];
  const float* fbhh1 = (const float*)d_in[8];
  const float* bWih0 = (const float*)d_in[9];
  const float* bWhh0 = (const float*)d_in[10];
  const float* bbih0 = (const float*)d_in[11];
  const float* bbhh0 = (const float*)d_in[12];
  const float* bWih1 = (const float*)d_in[13];
  const float* bWhh1 = (const float*)d_in[14];
  const float* bbih1 = (const float*)d_in[15];
  const float* bbhh1 = (const float*)d_in[16];
  float* out = (float*)d_out;

  // workspace: P[2][4096][2048] fp32 (67 MB), ex0/ex1 [2][S_SLOT][512] u64 each, progress flags
  float* P_f = (float*)d_ws;
  float* P_b = P_f + (size_t)T_SEQ*NGATE;
  u64*   ex0 = (u64*)(P_b + (size_t)T_SEQ*NGATE);
  u64*   ex1 = ex0 + 2*S_SLOT*HSZ;
  u32*   prog0 = (u32*)(ex1 + 2*S_SLOT*HSZ);
  u32*   prog1 = prog0 + 2*NB0;

  init_sync_kernel<<<32, 1024, 0, stream>>>(ex0, prog0);

  // layer-0 input projections for both directions (bwd reads P reversed in time)
  gemm_bias_kernel<<<dim3(32,16,2), 256, 0, stream>>>(
      emb, emb, fWih0, bWih0, fbih0, fbhh0, bbih0, bbhh0, P_f, P_b, DIN);

  // fused pipelined recurrence: L0 fwd/bwd + L1 fwd/bwd in one persistent launch
  fused_recur_kernel<<<96, 512, 0, stream>>>(
      fWhh0, bWhh0,
      fWih1, fWhh1, fbih1, fbhh1,
      bWih1, bWhh1, bbih1, bbhh1,
      P_f, P_b, ex0, ex1, prog0, prog1, out);
}

// Round 10
// 7091.386 us; speedup vs baseline: 4.5063x; 1.7242x over previous
//
#include <hip/hip_runtime.h>
#include <cstdint>
#include <cstddef>

#define T_SEQ 4096
#define HSZ   512
#define NGATE 2048   // 4*HSZ
#define DIN   1024
#define NB0   32     // layer-0 blocks per direction
#define HB0   16     // h-elements per layer-0 block
#define NB1   64     // layer-1 blocks per direction
#define HB1   8      // h-elements per layer-1 block
#define S_SLOT 16    // exchange ring slots (power of 2)
#define CH0   68     // skewed LDS chunk stride in floats (64 + 4; 272B = 16B-aligned)

typedef unsigned long long u64;
typedef unsigned int u32;

__device__ __forceinline__ u64 exld(const u64* p) {
  return __hip_atomic_load(p, __ATOMIC_RELAXED, __HIP_MEMORY_SCOPE_AGENT);
}
__device__ __forceinline__ void exst(u64* p, u64 v) {
  __hip_atomic_store(p, v, __ATOMIC_RELAXED, __HIP_MEMORY_SCOPE_AGENT);
}
__device__ __forceinline__ int pgld(const u32* p) {
  return (int)__hip_atomic_load(p, __ATOMIC_RELAXED, __HIP_MEMORY_SCOPE_AGENT);
}
__device__ __forceinline__ void pgst(u32* p, u32 v) {
  __hip_atomic_store(p, v, __ATOMIC_RELAXED, __HIP_MEMORY_SCOPE_AGENT);
}

// fast activations: v_rcp + v_exp (no div sequences, no libm tanh)
__device__ __forceinline__ float frcp(float x) { return __builtin_amdgcn_rcpf(x); }
__device__ __forceinline__ float fsig(float x) { return frcp(1.f + __expf(-x)); }
__device__ __forceinline__ float ftnh(float x) { return 1.f - 2.f * frcp(1.f + __expf(2.f * x)); }

// ---------------- init: zero exchange slots (epoch0 == h_0 == 0) + progress flags ----------------
__global__ void init_sync_kernel(u64* ex, u32* prog) {
  const int tid = blockIdx.x * blockDim.x + threadIdx.x;
  if (tid < 2 * 2 * S_SLOT * HSZ) exst(&ex[tid], 0ull);
  if (tid < 2 * (NB0 + NB1)) pgst(&prog[tid], 0u);
}

// ---------------- fp32 GEMM with bias: P[t,r] = sum_k X[t,k]*W[r,k] + bi[r] + bh[r] ----------------
__global__ __launch_bounds__(256, 2)
void gemm_bias_kernel(const float* __restrict__ Xf, const float* __restrict__ Xb,
                      const float* __restrict__ Wf, const float* __restrict__ Wb,
                      const float* __restrict__ bif, const float* __restrict__ bhf,
                      const float* __restrict__ bib, const float* __restrict__ bhb,
                      float* __restrict__ Pf, float* __restrict__ Pb, int K)
{
  const int dir = blockIdx.z;
  const float* X  = dir ? Xb  : Xf;
  const float* W  = dir ? Wb  : Wf;
  const float* bi = dir ? bib : bif;
  const float* bh = dir ? bhb : bhf;
  float* P        = dir ? Pb  : Pf;

  const int m0 = blockIdx.x * 128;
  const int n0 = blockIdx.y * 128;
  const int tid = threadIdx.x;
  const int lr = tid >> 1;
  const int lk = (tid & 1) * 8;

  __shared__ float As[16*128];
  __shared__ float Bs[16*128];

  float acc[8][8];
  #pragma unroll
  for (int i = 0; i < 8; ++i)
    #pragma unroll
    for (int j = 0; j < 8; ++j) acc[i][j] = 0.f;

  for (int k0 = 0; k0 < K; k0 += 16) {
    const float4 a0 = *(const float4*)(X + (size_t)(m0+lr)*K + k0 + lk);
    const float4 a1 = *(const float4*)(X + (size_t)(m0+lr)*K + k0 + lk + 4);
    const float4 b0 = *(const float4*)(W + (size_t)(n0+lr)*K + k0 + lk);
    const float4 b1 = *(const float4*)(W + (size_t)(n0+lr)*K + k0 + lk + 4);
    __syncthreads();
    As[(lk+0)*128+lr]=a0.x; As[(lk+1)*128+lr]=a0.y; As[(lk+2)*128+lr]=a0.z; As[(lk+3)*128+lr]=a0.w;
    As[(lk+4)*128+lr]=a1.x; As[(lk+5)*128+lr]=a1.y; As[(lk+6)*128+lr]=a1.z; As[(lk+7)*128+lr]=a1.w;
    Bs[(lk+0)*128+lr]=b0.x; Bs[(lk+1)*128+lr]=b0.y; Bs[(lk+2)*128+lr]=b0.z; Bs[(lk+3)*128+lr]=b0.w;
    Bs[(lk+4)*128+lr]=b1.x; Bs[(lk+5)*128+lr]=b1.y; Bs[(lk+6)*128+lr]=b1.z; Bs[(lk+7)*128+lr]=b1.w;
    __syncthreads();
    #pragma unroll
    for (int kk = 0; kk < 16; ++kk) {
      const float4 A0 = *(const float4*)(As + kk*128 + (tid&15)*8);
      const float4 A1 = *(const float4*)(As + kk*128 + (tid&15)*8 + 4);
      const float4 B0 = *(const float4*)(Bs + kk*128 + (tid>>4)*8);
      const float4 B1 = *(const float4*)(Bs + kk*128 + (tid>>4)*8 + 4);
      const float av[8] = {A0.x,A0.y,A0.z,A0.w,A1.x,A1.y,A1.z,A1.w};
      const float bv[8] = {B0.x,B0.y,B0.z,B0.w,B1.x,B1.y,B1.z,B1.w};
      #pragma unroll
      for (int i = 0; i < 8; ++i)
        #pragma unroll
        for (int j = 0; j < 8; ++j) acc[i][j] += av[i]*bv[j];
    }
  }
  const int tm = m0 + (tid&15)*8;
  const int tn = n0 + (tid>>4)*8;
  #pragma unroll
  for (int i = 0; i < 8; ++i) {
    #pragma unroll
    for (int j = 0; j < 8; ++j) {
      const int n = tn + j;
      P[(size_t)(tm+i)*NGATE + n] = acc[i][j] + bi[n] + bh[n];
    }
  }
}

// ---------------- fused persistent recurrence: both layers, both directions, pipelined ----------------
// blocks [0,64): L0 (fwd 0..31, bwd 32..63)   [64,192): L1 (fwd 64..127, bwd 128..191)
// Exchange: u64 = (epoch<<32)|float_bits into slot epoch&(S_SLOT-1), agent scope (LLC).
// R4: 16-slot ring + lazy guard (every 8 steps, >= t-4).  R5: in-wave gates, 1 barrier/step.
// R10: halved per-block output (2x blocks) so per-lane weights = 16 float4 = 64 VGPRs,
// fitting UNDER the allocator's ~128-reg occupancy budget -> weights stay register-resident
// (R5's w[32]=128 regs exceeded it -> per-step reloads; R9's asm pin forced a spill instead).
// Per-lane matvec work also halves (64 MACs).
__global__ __launch_bounds__(512, 2)
void fused_recur_kernel(const float* __restrict__ Whh0_f, const float* __restrict__ Whh0_b,
                        const float* __restrict__ Wih1_f, const float* __restrict__ Whh1_f,
                        const float* __restrict__ bih1_f, const float* __restrict__ bhh1_f,
                        const float* __restrict__ Wih1_b, const float* __restrict__ Whh1_b,
                        const float* __restrict__ bih1_b, const float* __restrict__ bhh1_b,
                        const float* __restrict__ P_f, const float* __restrict__ P_b,
                        u64* ex0, u64* ex1, u32* prog0, u32* prog1,
                        float* __restrict__ out)
{
  const int bx  = blockIdx.x;
  const int tid = threadIdx.x;
  const int lane = tid & 63;
  const int wv   = tid >> 6;

  __shared__ float xh[2][16*CH0];   // double-buffered skewed 64-float chunks

  if (bx < 2*NB0) {
    // ---------------- layer 0 ----------------
    const int dir = (bx >= NB0) ? 1 : 0;
    const int b   = bx - dir*NB0;
    const float* Whh = dir ? Whh0_b : Whh0_f;
    const float* P   = dir ? P_b    : P_f;
    u64* exS   = ex0 + (size_t)dir*S_SLOT*HSZ;   // self exchange (also read by layer 1)
    u32* prS   = prog0 + dir*NB0;
    u32* prL1  = prog1 + dir*NB1;

    // lane = cc*8 + el*4 + g : 8 col-chunks of 64; 4 gates of an element adjacent
    const int g  = lane & 3;
    const int el = (lane >> 2) & 1;
    const int cc = lane >> 3;            // 0..7
    const int e  = wv*2 + el;            // 0..15 per block
    const int grow = g*HSZ + b*HB0 + e;  // global gate-row
    const bool red0 = (cc == 0);
    const bool pub  = red0 && (g == 0);

    float4 w[16];                        // 64 cols/lane -> 64 VGPRs, stays resident
    {
      const float4* wp = (const float4*)(Whh + (size_t)grow*HSZ + cc*64);
      #pragma unroll
      for (int j = 0; j < 16; ++j) w[j] = wp[j];
    }

    float creg = 0.f;
    float pv = 0.f;
    if (red0) pv = P[(size_t)(dir ? (T_SEQ-1) : 0)*NGATE + grow];

    for (int t = 0; t < T_SEQ; ++t) {
      // slot-overwrite guard, every 8 steps (consumers: L0 peers + L1 blocks of this dir)
      if ((t & 7) == 0) {
        if (tid >= 64 && tid < 64+NB0)        { while (pgld(&prS[tid-64])  < t-4) {} }
        else if (tid >= 96 && tid < 96+NB1)   { while (pgld(&prL1[tid-96]) < t-4) {} }
      }
      // poll h_t (epoch t), stage to skewed LDS: chunk tid>>6, offset tid&63
      {
        const u64* sp = exS + (size_t)(t & (S_SLOT-1))*HSZ + tid;
        u64 v;
        do { v = exld(sp); } while ((u32)(v >> 32) != (u32)t);
        xh[t & 1][(tid>>6)*CH0 + (tid & 63)] = __uint_as_float((u32)v);
      }
      __syncthreads();
      if (tid == 0) pgst(&prS[b], (u32)(t+1));   // epoch-t reads complete
      // next-step P prefetch (one step of miss-hiding)
      float pvn = 0.f;
      if (red0 && t+1 < T_SEQ) pvn = P[(size_t)(dir ? (T_SEQ-2-t) : (t+1))*NGATE + grow];
      // matvec: 16 float4 from chunk cc (8 chunks x stride-68 floats: conflict-free)
      const float4* h4 = (const float4*)(xh[t & 1] + cc*CH0);
      float a0=0.f, a1=0.f, a2=0.f, a3=0.f;
      #pragma unroll
      for (int j = 0; j < 16; j += 4) {
        const float4 h0 = h4[j], h1 = h4[j+1], h2 = h4[j+2], h3 = h4[j+3];
        a0 += w[j].x*h0.x   + w[j].y*h0.y   + w[j].z*h0.z   + w[j].w*h0.w;
        a1 += w[j+1].x*h1.x + w[j+1].y*h1.y + w[j+1].z*h1.z + w[j+1].w*h1.w;
        a2 += w[j+2].x*h2.x + w[j+2].y*h2.y + w[j+2].z*h2.z + w[j+2].w*h2.w;
        a3 += w[j+3].x*h3.x + w[j+3].y*h3.y + w[j+3].z*h3.z + w[j+3].w*h3.w;
      }
      float acc = (a0+a1)+(a2+a3);
      acc += __shfl_xor(acc, 8);           // reduce over cc (lane bits 3,4,5)
      acc += __shfl_xor(acc, 16);
      acc += __shfl_xor(acc, 32);
      const float val = acc + pv;          // full row value on cc==0 lanes
      pv = pvn;
      // parallel activation on the 4 gate lanes, then gather
      const float av = (g == 2) ? ftnh(val) : fsig(val);
      const float f1 = __shfl_xor(av, 1);
      const float f2 = __shfl_xor(av, 2);
      const float f3 = __shfl_xor(av, 3);
      if (pub) {
        // lane g=0: av=sig(i); f1=sig(f); f2=tanh(g); f3=sig(o)
        creg = f1*creg + av*f2;
        const float hnew = f3*ftnh(creg);
        const int hidx = b*HB0 + e;
        const u64 pkt = ((u64)(u32)(t+1) << 32) | (u64)__float_as_uint(hnew);
        exst(exS + (size_t)((t+1) & (S_SLOT-1))*HSZ + hidx, pkt);
        if (t == T_SEQ-1) {
          out[dir*HSZ + hidx]        = creg;   // cell_memories layer 0
          out[2048 + dir*HSZ + hidx] = hnew;   // hidden_states layer 0
        }
      }
    }
  } else {
    // ---------------- layer 1 ----------------
    const int r   = bx - 2*NB0;
    const int dir = (r >= NB1) ? 1 : 0;
    const int b   = r - dir*NB1;
    const float* Wih = dir ? Wih1_b : Wih1_f;
    const float* Whh = dir ? Whh1_b : Whh1_f;
    const float* bi  = dir ? bih1_b : bih1_f;
    const float* bh  = dir ? bhh1_b : bhh1_f;
    u64* exX = ex0 + (size_t)dir*S_SLOT*HSZ;     // x source = layer-0 outputs
    u64* exS = ex1 + (size_t)dir*S_SLOT*HSZ;     // self h exchange
    u32* prS = prog1 + dir*NB1;

    // lane = cc*4 + g : 16 col-chunks of 64 (0-7: Wih/x, 8-15: Whh/h); wave = element
    const int g  = lane & 3;
    const int cc = lane >> 2;            // 0..15
    const int e  = wv;                   // 0..7 per block
    const int grow = g*HSZ + b*HB1 + e;
    const bool red0 = (cc == 0);
    const bool pub  = red0 && (g == 0);

    float4 w[16];                        // 64 cols/lane -> 64 VGPRs, stays resident
    {
      const float* wsrc = (cc < 8) ? (Wih + (size_t)grow*HSZ + cc*64)
                                   : (Whh + (size_t)grow*HSZ + (cc-8)*64);
      const float4* wp = (const float4*)wsrc;
      #pragma unroll
      for (int j = 0; j < 16; ++j) w[j] = wp[j];
    }
    float brow = 0.f;
    if (red0) brow = bi[grow] + bh[grow];

    float creg = 0.f;
    u64 xpf = exld(exX + (size_t)(1 & (S_SLOT-1))*HSZ + tid);   // prefetch x epoch 1

    for (int t = 0; t < T_SEQ; ++t) {
      // slot-overwrite guard, every 8 steps (consumers of ex1: L1 peers of this dir)
      if ((t & 7) == 0 && tid >= 64 && tid < 64+NB1) { while (pgld(&prS[tid-64]) < t-4) {} }
      // poll x_t (epoch t+1; usually satisfied by prefetch) and own h_t (epoch t)
      {
        const u64* px = exX + (size_t)((t+1) & (S_SLOT-1))*HSZ + tid;
        const u64* ph = exS + (size_t)(t & (S_SLOT-1))*HSZ + tid;
        u64 vx = xpf; bool okx = ((u32)(vx >> 32) == (u32)(t+1));
        float hv = 0.f; bool okh = false;
        do {
          if (!okx) { u64 v = exld(px); if ((u32)(v >> 32) == (u32)(t+1)) { vx = v; okx = true; } }
          if (!okh) { u64 v = exld(ph); if ((u32)(v >> 32) == (u32)t)     { hv = __uint_as_float((u32)v); okh = true; } }
        } while (!(okx && okh));
        xh[t & 1][(tid>>6)*CH0 + (tid & 63)]       = __uint_as_float((u32)vx);   // chunks 0..7 (x)
        xh[t & 1][(8 + (tid>>6))*CH0 + (tid & 63)] = hv;                         // chunks 8..15 (h)
      }
      __syncthreads();
      if (tid == 0) pgst(&prS[b], (u32)(t+1));
      xpf = exld(exX + (size_t)((t+2) & (S_SLOT-1))*HSZ + tid);   // prefetch next x (epoch-tagged)
      // matvec: 16 float4 from chunk cc
      const float4* v4 = (const float4*)(xh[t & 1] + cc*CH0);
      float a0=0.f, a1=0.f, a2=0.f, a3=0.f;
      #pragma unroll
      for (int j = 0; j < 16; j += 4) {
        const float4 h0 = v4[j], h1 = v4[j+1], h2 = v4[j+2], h3 = v4[j+3];
        a0 += w[j].x*h0.x   + w[j].y*h0.y   + w[j].z*h0.z   + w[j].w*h0.w;
        a1 += w[j+1].x*h1.x + w[j+1].y*h1.y + w[j+1].z*h1.z + w[j+1].w*h1.w;
        a2 += w[j+2].x*h2.x + w[j+2].y*h2.y + w[j+2].z*h2.z + w[j+2].w*h2.w;
        a3 += w[j+3].x*h3.x + w[j+3].y*h3.y + w[j+3].z*h3.z + w[j+3].w*h3.w;
      }
      float acc = (a0+a1)+(a2+a3);
      acc += __shfl_xor(acc, 4);           // reduce over cc (lane bits 2,3,4,5)
      acc += __shfl_xor(acc, 8);
      acc += __shfl_xor(acc, 16);
      acc += __shfl_xor(acc, 32);
      const float val = acc + brow;
      const float av = (g == 2) ? ftnh(val) : fsig(val);
      const float f1 = __shfl_xor(av, 1);
      const float f2 = __shfl_xor(av, 2);
      const float f3 = __shfl_xor(av, 3);
      if (pub) {
        creg = f1*creg + av*f2;
        const float hnew = f3*ftnh(creg);
        const int hidx = b*HB1 + e;
        const u64 pkt = ((u64)(u32)(t+1) << 32) | (u64)__float_as_uint(hnew);
        exst(exS + (size_t)((t+1) & (S_SLOT-1))*HSZ + hidx, pkt);
        const int trow = dir ? (T_SEQ-1-t) : t;
        out[4096 + (size_t)trow*1024 + dir*HSZ + hidx] = hnew;   // top-layer outputs
        if (t == T_SEQ-1) {
          out[1024 + dir*HSZ + hidx]        = creg;   // cell_memories layer 1
          out[2048 + 1024 + dir*HSZ + hidx] = hnew;   // hidden_states layer 1
        }
      }
    }
  }
}

// ---------------- launch ----------------
extern "C" void kernel_launch(void* const* d_in, const int* in_sizes, int n_in,
                              void* d_out, int out_size, void* d_ws, size_t ws_size,
                              hipStream_t stream)
{
  const float* emb   = (const float*)d_in[0];
  const float* fWih0 = (const float*)d_in[1];
  const float* fWhh0 = (const float*)d_in[2];
  const float* fbih0 = (const float*)d_in[3];
  const float* fbhh0 = (const float*)d_in[4];
  const float* fWih1 = (const float*)d_in[5];
  const float* fWhh1 = (const float*)d_in[6];
  const float* fbih1 = (const float*)d_in[7];
  const float* fbhh1 = (const float*)d_in[8];
  const float* bWih0 = (const float*)d_in[9];
  const float* bWhh0 = (const float*)d_in[10];
  const float* bbih0 = (const float*)d_in[11];
  const float* bbhh0 = (const float*)d_in[12];
  const float* bWih1 = (const float*)d_in[13];
  const float* bWhh1 = (const float*)d_in[14];
  const float* bbih1 = (const float*)d_in[15];
  const float* bbhh1 = (const float*)d_in[16];
  float* out = (float*)d_out;

  // workspace: P[2][4096][2048] fp32 (67 MB), ex0/ex1 [2][S_SLOT][512] u64 each, progress flags
  float* P_f = (float*)d_ws;
  float* P_b = P_f + (size_t)T_SEQ*NGATE;
  u64*   ex0 = (u64*)(P_b + (size_t)T_SEQ*NGATE);
  u64*   ex1 = ex0 + 2*S_SLOT*HSZ;
  u32*   prog0 = (u32*)(ex1 + 2*S_SLOT*HSZ);
  u32*   prog1 = prog0 + 2*NB0;

  init_sync_kernel<<<32, 1024, 0, stream>>>(ex0, prog0);

  // layer-0 input projections for both directions (bwd reads P reversed in time)
  gemm_bias_kernel<<<dim3(32,16,2), 256, 0, stream>>>(
      emb, emb, fWih0, bWih0, fbih0, fbhh0, bbih0, bbhh0, P_f, P_b, DIN);

  // fused pipelined recurrence: L0 fwd/bwd + L1 fwd/bwd in one persistent launch
  fused_recur_kernel<<<2*NB0 + 2*NB1, 512, 0, stream>>>(
      fWhh0, bWhh0,
      fWih1, fWhh1, fbih1, fbhh1,
      bWih1, bWhh1, bbih1, bbhh1,
      P_f, P_b, ex0, ex1, prog0, prog1, out);
}